// Round 16
// baseline (55.804 us; speedup 1.0000x reference)
//
#include <hip/hip_runtime.h>
#include <math.h>

namespace {

constexpr int T_ = 1024;
constexpr int HKV_ = 8;
constexpr int M_ = 8;
constexpr int D_ = 64;
constexpr int WIN_ = 128;
constexpr float SCALE_ = 0.125f;   // 1/sqrt(64)

constexpr int IB_ = 16;            // query rows per block (1 per wave, 16 waves)
constexpr int NKEY_ = 144;         // staged keys: [i0-127, i0+16]
constexpr int NTHREADS_ = 1024;

using f4 = __attribute__((ext_vector_type(4))) float;

// float -> bf16 (round-nearest-even), packed pair
__device__ inline unsigned bf16rne_pack(float x, float y) {
    unsigned bx = __float_as_uint(x);
    unsigned by = __float_as_uint(y);
    bx = (bx + 0x7FFFu + ((bx >> 16) & 1u)) >> 16;
    by = (by + 0x7FFFu + ((by >> 16) & 1u)) >> 16;
    return bx | (by << 16);
}

// ---- wave64 reductions on the VALU pipe (DPP), not the DS pipe ----
template <int CTRL>
__device__ inline float dpp_max_step(float x) {
    int yi = __builtin_amdgcn_update_dpp(__float_as_int(x), __float_as_int(x),
                                         CTRL, 0xF, 0xF, false);
    return fmaxf(x, __int_as_float(yi));
}
template <int CTRL>
__device__ inline float dpp_add_step(float x) {
    int yi = __builtin_amdgcn_update_dpp(0, __float_as_int(x),
                                         CTRL, 0xF, 0xF, true);
    return x + __int_as_float(yi);
}
__device__ inline float wave_max64(float x) {
    x = dpp_max_step<0x111>(x);   // row_shr:1
    x = dpp_max_step<0x112>(x);   // row_shr:2
    x = dpp_max_step<0x114>(x);   // row_shr:4
    x = dpp_max_step<0x118>(x);   // row_shr:8
    x = dpp_max_step<0x142>(x);   // row_bcast:15
    x = dpp_max_step<0x143>(x);   // row_bcast:31
    return __int_as_float(__builtin_amdgcn_readlane(__float_as_int(x), 63));
}
__device__ inline float wave_sum64(float x) {
    x = dpp_add_step<0x111>(x);
    x = dpp_add_step<0x112>(x);
    x = dpp_add_step<0x114>(x);
    x = dpp_add_step<0x118>(x);
    x = dpp_add_step<0x142>(x);
    x = dpp_add_step<0x143>(x);
    return __int_as_float(__builtin_amdgcn_readlane(__float_as_int(x), 63));
}

// R15 per-wave code UNCHANGED; ONE structural change: 16 waves/block
// (IB=16, 1024 threads), grid 512 = exactly 2 blocks/CU = FULLY RESIDENT.
// Eliminates the 4-sequential-batch store bubbles (each batch opened with
// a store-silent staging+fma phase); K window staged once per 16 rows
// instead of 8 (halves FETCH). Per-wave register/code shape identical to
// the 53.6us champion -> no spill risk (R11's failure was a
// runtime-selected pointer to locals, not IB itself).
// Kept lessons: STRAIGHT-LINE all-4-chunk epilogue (branchy/skip =>
// ~0.5-1GB symmetric FETCH/WRITE tax); plain cached f4 full-line stores;
// no global vector loads post-barrier; no launch_bounds; DPP reduces;
// fence-free pipelined epilogue.
__global__ void attn_qk_softmax(const float* __restrict__ qg,
                                const float* __restrict__ kg,
                                const float* __restrict__ sinks,
                                float* __restrict__ outg)
{
    __shared__ float    k_lds[NKEY_ * D_];       // XOR-swizzled keys (36.9 KB)
    __shared__ unsigned q_lds[IB_][M_ * D_ / 2]; // bf16-packed q rows (16 KB)
    __shared__ float    p_lds[IB_][2][136];      // pad-17 probs, dbuf (17.4 KB)

    const int tid  = threadIdx.x;
    const int wave = tid >> 6;
    const int lane = tid & 63;
    const int h    = blockIdx.x / (T_ / IB_);
    const int i0   = (blockIdx.x % (T_ / IB_)) * IB_;
    const int base = i0 - (WIN_ - 1);            // global j of staged key r=0

    // ---- stage K window into LDS (swizzled: c4 ^= ((r>>1)&7)<<2) ----
    for (int f = tid; f < NKEY_ * (D_ / 4); f += NTHREADS_) {
        const int r  = f >> 4;
        const int c4 = (f & 15) << 2;
        const int j  = base + r;
        f4 v = {0.f, 0.f, 0.f, 0.f};
        if ((unsigned)j < (unsigned)T_)
            v = *reinterpret_cast<const f4*>(kg + ((size_t)j * HKV_ + h) * D_ + c4);
        const int sw = c4 ^ (((r >> 1) & 7) << 2);
        *reinterpret_cast<f4*>(&k_lds[r * D_ + sw]) = v;
    }
    // ---- stage this wave's q rows as packed bf16 ----
    {
        const int i = i0 + wave;
        const float* qp = qg + ((size_t)i * HKV_ + h) * (M_ * D_);
        const int off = lane * 4;                // float index within the row
        const f4 a = *reinterpret_cast<const f4*>(qp + off);
        const f4 b = *reinterpret_cast<const f4*>(qp + off + 256);
        uint2 pa, pb2;
        pa.x  = bf16rne_pack(a.x, a.y);
        pa.y  = bf16rne_pack(a.z, a.w);
        pb2.x = bf16rne_pack(b.x, b.y);
        pb2.y = bf16rne_pack(b.z, b.w);
        *reinterpret_cast<uint2*>(&q_lds[wave][off / 2])         = pa;
        *reinterpret_cast<uint2*>(&q_lds[wave][(off + 256) / 2]) = pb2;
    }
    __syncthreads();

    const int i   = i0 + wave;
    const int jlo = (i >= WIN_ - 1) ? (i - (WIN_ - 1)) : 0;
    const int cnt = i - jlo + 1;                 // 1..128 valid keys
    const int rlo = jlo - base;                  // rel idx of first valid key

    const int idx0 = 2 * lane;
    const int idx1 = idx0 + 1;
    const bool v0 = idx0 < cnt;
    const bool v1 = idx1 < cnt;
    int r0 = rlo + idx0; if (r0 > NKEY_ - 1) r0 = NKEY_ - 1;
    int r1 = rlo + idx1; if (r1 > NKEY_ - 1) r1 = NKEY_ - 1;

    float acc0[M_], acc1[M_];
    #pragma unroll
    for (int m = 0; m < M_; ++m) { acc0[m] = 0.f; acc1[m] = 0.f; }

    const float* k0p = &k_lds[r0 * D_];
    const float* k1p = &k_lds[r1 * D_];
    const int sw0 = ((r0 >> 1) & 7) << 2;
    const int sw1 = ((r1 >> 1) & 7) << 2;

    #pragma unroll
    for (int c = 0; c < 16; ++c) {
        const int c4 = c << 2;
        const f4 kv0 = *reinterpret_cast<const f4*>(k0p + (c4 ^ sw0));
        const f4 kv1 = *reinterpret_cast<const f4*>(k1p + (c4 ^ sw1));
        #pragma unroll
        for (int m = 0; m < M_; ++m) {
            // wave-uniform broadcast read of 4 bf16-packed q values (8B)
            const uint2 qw = *reinterpret_cast<const uint2*>(
                &q_lds[wave][(m * D_ + c4) / 2]);
            const float q0 = __uint_as_float(qw.x << 16);
            const float q1 = __uint_as_float(qw.x & 0xFFFF0000u);
            const float q2 = __uint_as_float(qw.y << 16);
            const float q3 = __uint_as_float(qw.y & 0xFFFF0000u);
            acc0[m] = fmaf(q0, kv0.x, acc0[m]);
            acc0[m] = fmaf(q1, kv0.y, acc0[m]);
            acc0[m] = fmaf(q2, kv0.z, acc0[m]);
            acc0[m] = fmaf(q3, kv0.w, acc0[m]);
            acc1[m] = fmaf(q0, kv1.x, acc1[m]);
            acc1[m] = fmaf(q1, kv1.y, acc1[m]);
            acc1[m] = fmaf(q2, kv1.z, acc1[m]);
            acc1[m] = fmaf(q3, kv1.w, acc1[m]);
        }
    }

    // ---- pipelined epilogue: softmax(m)+bounce(m), then store row m-1 ----
    #define STORE_ROW(mm)                                                     \
    {                                                                         \
        const float* pbr = p_lds[wave][(mm) & 1];                             \
        float* orow = outg + (((size_t)(h * M_ + (mm)) * T_ + i) * T_);       \
        _Pragma("unroll")                                                     \
        for (int t = 0; t < 4; ++t) {                                         \
            const int j = t * 256 + lane * 4;                                 \
            f4 ov;                                                            \
            _Pragma("unroll")                                                 \
            for (int u = 0; u < 4; ++u) {                                     \
                int idx = j + u - jlo;                                        \
                const bool in = (unsigned)idx < (unsigned)cnt;                \
                int ci = idx; if (ci < 0) ci = 0; if (ci > 127) ci = 127;     \
                const float val = pbr[ci + (ci >> 4)];                        \
                ov[u] = in ? val : 0.0f;                                      \
            }                                                                 \
            *reinterpret_cast<f4*>(orow + j) = ov;                            \
        }                                                                     \
    }

    #pragma unroll
    for (int m = 0; m < M_; ++m) {
        float l0 = v0 ? acc0[m] * SCALE_ : -INFINITY;
        float l1 = v1 ? acc1[m] * SCALE_ : -INFINITY;
        float mx = wave_max64(fmaxf(l0, l1));    // VALU-pipe reduce
        const float slog = sinks[h * M_ + m];
        mx = fmaxf(mx, slog);
        float p0 = __expf(l0 - mx);              // exp(-inf)=0 for masked keys
        float p1 = __expf(l1 - mx);
        const float sum = wave_sum64(p0 + p1);   // VALU-pipe reduce
        const float inv = 1.0f / (sum + __expf(slog - mx));
        p0 *= inv;
        p1 *= inv;

        float* pb = p_lds[wave][m & 1];          // double buffer
        pb[idx0 + (idx0 >> 4)] = p0;
        pb[idx1 + (idx1 >> 4)] = p1;
        // no fence: same-wave DS ops are pipe-ordered; compiler inserts
        // fine-grained lgkmcnt before the gather's data use.

        if (m >= 1) STORE_ROW(m - 1);            // m literal when unrolled
    }
    STORE_ROW(M_ - 1);
    #undef STORE_ROW
}

} // namespace

extern "C" void kernel_launch(void* const* d_in, const int* in_sizes, int n_in,
                              void* d_out, int out_size, void* d_ws, size_t ws_size,
                              hipStream_t stream) {
    const float* q     = (const float*)d_in[0];
    const float* k     = (const float*)d_in[1];
    const float* sinks = (const float*)d_in[2];
    float* out         = (float*)d_out;

    dim3 grid(HKV_ * (T_ / IB_));   // 8 heads * 64 i-blocks = 512 blocks (2/CU)
    attn_qk_softmax<<<grid, NTHREADS_, 0, stream>>>(q, k, sinks, out);
}

// Round 17
// 53.777 us; speedup vs baseline: 1.0377x; 1.0377x over previous
//
#include <hip/hip_runtime.h>
#include <math.h>

namespace {

constexpr int T_ = 1024;
constexpr int HKV_ = 8;
constexpr int M_ = 8;
constexpr int D_ = 64;
constexpr int WIN_ = 128;
constexpr float SCALE_ = 0.125f;   // 1/sqrt(64)

constexpr int IB_ = 8;             // query rows per block (1 per wave)
constexpr int NKEY_ = 136;         // staged keys: [i0-127, i0+8]
constexpr int NTHREADS_ = 512;

using f4 = __attribute__((ext_vector_type(4))) float;

// float -> bf16 (round-nearest-even), packed pair
__device__ inline unsigned bf16rne_pack(float x, float y) {
    unsigned bx = __float_as_uint(x);
    unsigned by = __float_as_uint(y);
    bx = (bx + 0x7FFFu + ((bx >> 16) & 1u)) >> 16;
    by = (by + 0x7FFFu + ((by >> 16) & 1u)) >> 16;
    return bx | (by << 16);
}

// ---- wave64 reductions on the VALU pipe (DPP), not the DS pipe ----
template <int CTRL>
__device__ inline float dpp_max_step(float x) {
    int yi = __builtin_amdgcn_update_dpp(__float_as_int(x), __float_as_int(x),
                                         CTRL, 0xF, 0xF, false);
    return fmaxf(x, __int_as_float(yi));
}
template <int CTRL>
__device__ inline float dpp_add_step(float x) {
    int yi = __builtin_amdgcn_update_dpp(0, __float_as_int(x),
                                         CTRL, 0xF, 0xF, true);
    return x + __int_as_float(yi);
}
__device__ inline float wave_max64(float x) {
    x = dpp_max_step<0x111>(x);   // row_shr:1
    x = dpp_max_step<0x112>(x);   // row_shr:2
    x = dpp_max_step<0x114>(x);   // row_shr:4
    x = dpp_max_step<0x118>(x);   // row_shr:8
    x = dpp_max_step<0x142>(x);   // row_bcast:15
    x = dpp_max_step<0x143>(x);   // row_bcast:31
    return __int_as_float(__builtin_amdgcn_readlane(__float_as_int(x), 63));
}
__device__ inline float wave_sum64(float x) {
    x = dpp_add_step<0x111>(x);
    x = dpp_add_step<0x112>(x);
    x = dpp_add_step<0x114>(x);
    x = dpp_add_step<0x118>(x);
    x = dpp_add_step<0x142>(x);
    x = dpp_add_step<0x143>(x);
    return __int_as_float(__builtin_amdgcn_readlane(__float_as_int(x), 63));
}

// FINAL: round-13 champion (53.6us, clean counters), reverted verbatim.
// Structure: 8 waves x 1 query row; K window f32 XOR-swizzled in LDS;
// q bf16-packed in LDS (wave-uniform broadcast reads); per-m softmax with
// sink via DPP (VALU-pipe) reductions; pad-17 double-buffered LDS bounce;
// full-row straight-line epilogue of 4 plain cached f4 stores per lane
// (each instruction = 1KB contiguous = 8 full 128B lines).
// Session laws baked in:
//  - NT or partial-line stores => write-allocate/RMW tax (R1-R3: 2.5x+)
//  - branchy/skip store epilogues => ~0.5-1GB symmetric FETCH/WRITE tax
//    (R6/R7/R14); keep the epilogue straight-line, all 4 chunks
//  - VGPR caps / runtime-selected pointers to locals => scratch spill
//    (R6/R11); no launch_bounds
//  - no global vector loads post-barrier (vmcnt shared with stores, R8)
//  - occupancy/residency/phasing moves all <=1-2us (R9/R10/R15/R16)
__global__ void attn_qk_softmax(const float* __restrict__ qg,
                                const float* __restrict__ kg,
                                const float* __restrict__ sinks,
                                float* __restrict__ outg)
{
    __shared__ float    k_lds[NKEY_ * D_];       // XOR-swizzled keys (34.8 KB)
    __shared__ unsigned q_lds[IB_][M_ * D_ / 2]; // bf16-packed q rows (8 KB)
    __shared__ float    p_lds[IB_][2][136];      // pad-17 probs, dbuf (8.7 KB)

    const int tid  = threadIdx.x;
    const int wave = tid >> 6;
    const int lane = tid & 63;
    const int h    = blockIdx.x / (T_ / IB_);
    const int i0   = (blockIdx.x % (T_ / IB_)) * IB_;
    const int base = i0 - (WIN_ - 1);            // global j of staged key r=0

    // ---- stage K window into LDS (swizzled: c4 ^= ((r>>1)&7)<<2) ----
    for (int f = tid; f < NKEY_ * (D_ / 4); f += NTHREADS_) {
        const int r  = f >> 4;
        const int c4 = (f & 15) << 2;
        const int j  = base + r;
        f4 v = {0.f, 0.f, 0.f, 0.f};
        if ((unsigned)j < (unsigned)T_)
            v = *reinterpret_cast<const f4*>(kg + ((size_t)j * HKV_ + h) * D_ + c4);
        const int sw = c4 ^ (((r >> 1) & 7) << 2);
        *reinterpret_cast<f4*>(&k_lds[r * D_ + sw]) = v;
    }
    // ---- stage this wave's q rows as packed bf16 ----
    {
        const int i = i0 + wave;
        const float* qp = qg + ((size_t)i * HKV_ + h) * (M_ * D_);
        const int off = lane * 4;                // float index within the row
        const f4 a = *reinterpret_cast<const f4*>(qp + off);
        const f4 b = *reinterpret_cast<const f4*>(qp + off + 256);
        uint2 pa, pb2;
        pa.x  = bf16rne_pack(a.x, a.y);
        pa.y  = bf16rne_pack(a.z, a.w);
        pb2.x = bf16rne_pack(b.x, b.y);
        pb2.y = bf16rne_pack(b.z, b.w);
        *reinterpret_cast<uint2*>(&q_lds[wave][off / 2])         = pa;
        *reinterpret_cast<uint2*>(&q_lds[wave][(off + 256) / 2]) = pb2;
    }
    __syncthreads();

    const int i   = i0 + wave;
    const int jlo = (i >= WIN_ - 1) ? (i - (WIN_ - 1)) : 0;
    const int cnt = i - jlo + 1;                 // 1..128 valid keys
    const int rlo = jlo - base;                  // rel idx of first valid key

    const int idx0 = 2 * lane;
    const int idx1 = idx0 + 1;
    const bool v0 = idx0 < cnt;
    const bool v1 = idx1 < cnt;
    int r0 = rlo + idx0; if (r0 > NKEY_ - 1) r0 = NKEY_ - 1;
    int r1 = rlo + idx1; if (r1 > NKEY_ - 1) r1 = NKEY_ - 1;

    float acc0[M_], acc1[M_];
    #pragma unroll
    for (int m = 0; m < M_; ++m) { acc0[m] = 0.f; acc1[m] = 0.f; }

    const float* k0p = &k_lds[r0 * D_];
    const float* k1p = &k_lds[r1 * D_];
    const int sw0 = ((r0 >> 1) & 7) << 2;
    const int sw1 = ((r1 >> 1) & 7) << 2;

    #pragma unroll
    for (int c = 0; c < 16; ++c) {
        const int c4 = c << 2;
        const f4 kv0 = *reinterpret_cast<const f4*>(k0p + (c4 ^ sw0));
        const f4 kv1 = *reinterpret_cast<const f4*>(k1p + (c4 ^ sw1));
        #pragma unroll
        for (int m = 0; m < M_; ++m) {
            // wave-uniform broadcast read of 4 bf16-packed q values (8B)
            const uint2 qw = *reinterpret_cast<const uint2*>(
                &q_lds[wave][(m * D_ + c4) / 2]);
            const float q0 = __uint_as_float(qw.x << 16);
            const float q1 = __uint_as_float(qw.x & 0xFFFF0000u);
            const float q2 = __uint_as_float(qw.y << 16);
            const float q3 = __uint_as_float(qw.y & 0xFFFF0000u);
            acc0[m] = fmaf(q0, kv0.x, acc0[m]);
            acc0[m] = fmaf(q1, kv0.y, acc0[m]);
            acc0[m] = fmaf(q2, kv0.z, acc0[m]);
            acc0[m] = fmaf(q3, kv0.w, acc0[m]);
            acc1[m] = fmaf(q0, kv1.x, acc1[m]);
            acc1[m] = fmaf(q1, kv1.y, acc1[m]);
            acc1[m] = fmaf(q2, kv1.z, acc1[m]);
            acc1[m] = fmaf(q3, kv1.w, acc1[m]);
        }
    }

    // ---- per-m softmax (with sink, DPP reduces) + full-row plain store ----
    #pragma unroll
    for (int m = 0; m < M_; ++m) {
        float l0 = v0 ? acc0[m] * SCALE_ : -INFINITY;
        float l1 = v1 ? acc1[m] * SCALE_ : -INFINITY;
        float mx = wave_max64(fmaxf(l0, l1));    // VALU-pipe reduce
        const float slog = sinks[h * M_ + m];
        mx = fmaxf(mx, slog);
        float p0 = __expf(l0 - mx);              // exp(-inf)=0 for masked keys
        float p1 = __expf(l1 - mx);
        const float sum = wave_sum64(p0 + p1);   // VALU-pipe reduce
        const float inv = 1.0f / (sum + __expf(slog - mx));
        p0 *= inv;
        p1 *= inv;

        float* pb = p_lds[wave][m & 1];          // double buffer
        pb[idx0 + (idx0 >> 4)] = p0;
        pb[idx1 + (idx1 >> 4)] = p1;
        asm volatile("s_waitcnt lgkmcnt(0)" ::: "memory");  // writes visible

        // Full 4 KB row, 4 plain f4 stores per lane; each instruction covers
        // 1 KB contiguous = 8 full 128B lines sourced entirely from this wave.
        float* orow = outg + (((size_t)(h * M_ + m) * T_ + i) * T_);
        #pragma unroll
        for (int t = 0; t < 4; ++t) {
            const int j = t * 256 + lane * 4;    // float index in row
            f4 ov;
            #pragma unroll
            for (int u = 0; u < 4; ++u) {
                int idx = j + u - jlo;
                const bool in = (unsigned)idx < (unsigned)cnt;
                int ci = idx; if (ci < 0) ci = 0; if (ci > 127) ci = 127;
                const float val = pb[ci + (ci >> 4)];
                ov[u] = in ? val : 0.0f;
            }
            *reinterpret_cast<f4*>(orow + j) = ov;   // plain cached store
        }
    }
}

} // namespace

extern "C" void kernel_launch(void* const* d_in, const int* in_sizes, int n_in,
                              void* d_out, int out_size, void* d_ws, size_t ws_size,
                              hipStream_t stream) {
    const float* q     = (const float*)d_in[0];
    const float* k     = (const float*)d_in[1];
    const float* sinks = (const float*)d_in[2];
    float* out         = (float*)d_out;

    dim3 grid(HKV_ * (T_ / IB_));   // 8 heads * 128 i-blocks = 1024 blocks
    attn_qk_softmax<<<grid, NTHREADS_, 0, stream>>>(q, k, sinks, out);
}